// Round 4
// baseline (425.320 us; speedup 1.0000x reference)
//
#include <hip/hip_runtime.h>

typedef short bf16x8 __attribute__((ext_vector_type(8)));
typedef float f32x4  __attribute__((ext_vector_type(4)));

namespace {

constexpr int CIN = 32, CO = 32, Himg = 128, Wimg = 128, SY = 32, Bb = 4;
constexpr int IMG = Himg * Wimg;                 // 16384
constexpr int NT  = Bb * CO * IMG;               // new_target elems
constexpr int TROWS = 6, TQ = 17, TCOLS = 70;    // 6 rows x 17 col-quads staged
constexpr int NPIX  = TROWS * TCOLS;             // 420
constexpr int LDSB  = NPIX * 64;                 // 26880 B ([pixel][ci] bf16)
constexpr int RTASK = TROWS * TQ;                // 102 (row,quad) pairs
constexpr int NTHR  = 512;
constexpr int TPT   = 4;                         // staging tasks per thread
constexpr int SYC   = 8;                         // sy images per block

__device__ __forceinline__ int swz(int pix, int cb) {
  return (pix * 64 + cb) ^ ((pix & 7) << 4);
}
__device__ __forceinline__ unsigned cvtpk(float lo, float hi) {
  unsigned r;
  asm("v_cvt_pk_bf16_f32 %0, %1, %2" : "=v"(r) : "v"(lo), "v"(hi));
  return r;
}

__device__ __forceinline__ void task_decode(int t, int& ch, int& row, int& q, bool& act) {
  ch = t & 15;
  const int r = t >> 4;
  row = r / TQ;
  q   = r - row * TQ;
  act = (r < RTASK);
}

// burst-issue all global loads for one tile (aligned float4, 2 ci planes/task)
__device__ __forceinline__ void stage_load(f32x4 va[TPT], f32x4 vb[TPT],
                                           const float* __restrict__ src,
                                           int y0, int xq0, int tid)
{
  #pragma unroll
  for (int k = 0; k < TPT; ++k) {
    int ch, row, q; bool act;
    task_decode(tid + k * NTHR, ch, row, q, act);
    const int y = y0 - 1 + row;
    act = act && ((unsigned)y < (unsigned)Himg);
    f32x4 v0 = {0.f, 0.f, 0.f, 0.f}, v1 = {0.f, 0.f, 0.f, 0.f};
    if (act) {
      const float* p = src + (size_t)(2 * ch) * IMG + y * Wimg + 4 * (xq0 + q);
      v0 = *reinterpret_cast<const f32x4*>(p);
      v1 = *reinterpret_cast<const f32x4*>(p + IMG);
    }
    va[k] = v0; vb[k] = v1;
  }
}

// convert + write staged registers to LDS (swizzled [pixel][ci] bf16)
__device__ __forceinline__ void stage_write(const f32x4 va[TPT], const f32x4 vb[TPT],
                                            char* __restrict__ lds,
                                            int y0, int xq0, int x0, int tid)
{
  #pragma unroll
  for (int k = 0; k < TPT; ++k) {
    int ch, row, q; bool act;
    task_decode(tid + k * NTHR, ch, row, q, act);
    const int y = y0 - 1 + row;
    act = act && ((unsigned)y < (unsigned)Himg);
    if (act) {
      const int ix0 = 4 * (xq0 + q) - x0 + 1;   // lds column of elem 0
      #pragma unroll
      for (int e = 0; e < 4; ++e) {
        const int ix = ix0 + e;
        if (ix >= 0) {
          const int pix = row * TCOLS + ix;
          *reinterpret_cast<unsigned*>(lds + swz(pix, ch * 4)) =
              cvtpk(va[k][e], vb[k][e]);
        }
      }
    }
  }
}

// per-lane A fragments (weights) for this wave's single co-tile m
__device__ __forceinline__ void load_w(bf16x8 wf[9],
                                       const float* __restrict__ Wfull,
                                       int cioff, int m, int lane)
{
  const int lx = lane & 15, kc = lane >> 4;
  #pragma unroll
  for (int tap = 0; tap < 9; ++tap) {
    const float* base = Wfull + (size_t)((m * 16 + lx) * 64 + cioff + kc * 8) * 9 + tap;
    bf16x8 w;
    #pragma unroll
    for (int j = 0; j < 8; ++j) {
      unsigned u = __builtin_bit_cast(unsigned, base[j * 9]);
      w[j] = (short)((u + 0x7FFFu + ((u >> 16) & 1u)) >> 16);
    }
    wf[tap] = w;
  }
}

// 9-tap conv, one co-tile, 4 px-tiles
__device__ __forceinline__ void conv1(f32x4 acc[4],
                                      const char* __restrict__ lds,
                                      const bf16x8 wf[9],
                                      int row, int lane)
{
  const int lx = lane & 15, kc = lane >> 4;
  #pragma unroll
  for (int ky = 0; ky < 3; ++ky) {
    #pragma unroll
    for (int kx = 0; kx < 3; ++kx) {
      const int tap = ky * 3 + kx;
      #pragma unroll
      for (int n = 0; n < 4; ++n) {
        const int p = (row + ky) * TCOLS + n * 16 + lx + kx;
        const bf16x8 bfrag = *reinterpret_cast<const bf16x8*>(lds + swz(p, kc * 16));
        acc[n] = __builtin_amdgcn_mfma_f32_16x16x32_bf16(wf[tap], bfrag, acc[n], 0, 0, 0);
      }
    }
  }
}

__global__ __launch_bounds__(NTHR, 4)
void cross_mfma(const float* __restrict__ target,
                const float* __restrict__ support,
                const float* __restrict__ Wfull,
                const float* __restrict__ bias,
                float* __restrict__ out)
{
  __shared__ char lds[LDSB];

  const int tid  = threadIdx.x;
  const int lane = tid & 63;
  const int wv   = tid >> 6;            // 0..7
  const int row  = wv & 3;              // spatial row within band
  const int m    = wv >> 2;             // co half
  const int lx = lane & 15, kc = lane >> 4;

  const int bid = blockIdx.x;
  const int syq = bid & 3;              // sy quarter (8 images)
  const int xh  = (bid >> 2) & 1;
  const int yb  = (bid >> 3) & 31;
  const int b   = bid >> 8;
  const int y0 = yb * 4, x0 = xh * 64;
  const int y  = y0 + row;
  const int xq0 = xh ? 15 : 0;          // first aligned source quad

  // zero LDS once; statically-OOB cells stay zero across all iterations
  for (int e = tid; e < NPIX * 4; e += NTHR)
    reinterpret_cast<f32x4*>(lds)[e] = f32x4{0.f, 0.f, 0.f, 0.f};

  bf16x8 wf[9];
  load_w(wf, Wfull, 0, m, lane);                    // Wx

  f32x4 va[TPT], vb[TPT];
  stage_load(va, vb, target + (size_t)b * CIN * IMG, y0, xq0, tid);
  __syncthreads();                                  // zero-fill complete
  stage_write(va, vb, lds, y0, xq0, x0, tid);
  __syncthreads();                                  // target tile ready

  // cx = conv(target, Wx) + bias, reused across this block's sy images
  f32x4 cx[4];
  #pragma unroll
  for (int n = 0; n < 4; ++n) cx[n] = f32x4{0.f, 0.f, 0.f, 0.f};
  conv1(cx, lds, wf, row, lane);
  #pragma unroll
  for (int j = 0; j < 4; ++j) {
    const float bv = bias[m * 16 + kc * 4 + j];
    #pragma unroll
    for (int n = 0; n < 4; ++n) cx[n][j] += bv;
  }

  const float* supp0 = support + (size_t)(b * SY + syq * SYC) * CIN * IMG;
  stage_load(va, vb, supp0, y0, xq0, tid);          // issue sy-chunk img 0
  load_w(wf, Wfull, 32, m, lane);                   // switch to Wy
  __syncthreads();                                  // target-tile reads done
  stage_write(va, vb, lds, y0, xq0, x0, tid);

  f32x4 sum[4];
  #pragma unroll
  for (int n = 0; n < 4; ++n) sum[n] = f32x4{0.f, 0.f, 0.f, 0.f};
  __syncthreads();                                  // img 0 tile ready

  for (int i = 0; i < SYC; ++i) {
    if (i < SYC - 1)                                // burst-issue next tile
      stage_load(va, vb, supp0 + (size_t)(i + 1) * CIN * IMG, y0, xq0, tid);

    f32x4 acc[4];
    #pragma unroll
    for (int n = 0; n < 4; ++n) acc[n] = cx[n];
    conv1(acc, lds, wf, row, lane);
    __syncthreads();                                // all reads of tile i done

    if (i < SYC - 1)
      stage_write(va, vb, lds, y0, xq0, x0, tid);   // vmcnt wait hides here

    const int sy = syq * SYC + i;
    #pragma unroll
    for (int n = 0; n < 4; ++n) {
      sum[n] += acc[n];
      const size_t basei = (size_t)NT +
          (((size_t)(b * SY + sy) * CO + m * 16 + kc * 4) * Himg + y) * Wimg +
          x0 + n * 16 + lx;
      #pragma unroll
      for (int j = 0; j < 4; ++j)
        out[basei + (size_t)j * IMG] = acc[n][j];
    }
    __syncthreads();                                // tile i+1 fully written
  }

  // new_target partial: mean contribution of this sy chunk (+cx once, syq==0)
  #pragma unroll
  for (int n = 0; n < 4; ++n) {
    const size_t baseo =
        ((size_t)(b * CO + m * 16 + kc * 4) * Himg + y) * Wimg + x0 + n * 16 + lx;
    #pragma unroll
    for (int j = 0; j < 4; ++j) {
      const float cyPart = (sum[n][j] - (float)SYC * cx[n][j]) * (1.f / 32.f);
      const float v = cyPart + (syq == 0 ? cx[n][j] : 0.f);
      atomicAdd(&out[baseo + (size_t)j * IMG], v);
    }
  }
}

} // namespace

extern "C" void kernel_launch(void* const* d_in, const int* in_sizes, int n_in,
                              void* d_out, int out_size, void* d_ws, size_t ws_size,
                              hipStream_t stream)
{
  (void)in_sizes; (void)n_in; (void)out_size; (void)d_ws; (void)ws_size;
  const float* target  = (const float*)d_in[0];
  const float* support = (const float*)d_in[1];
  const float* Wfull   = (const float*)d_in[2];
  const float* bias    = (const float*)d_in[3];
  float* out = (float*)d_out;

  hipMemsetAsync(d_out, 0, (size_t)NT * sizeof(float), stream);
  cross_mfma<<<dim3(1024), NTHR, 0, stream>>>(target, support, Wfull, bias, out);
}

// Round 5
// 390.591 us; speedup vs baseline: 1.0889x; 1.0889x over previous
//
#include <hip/hip_runtime.h>

typedef short bf16x8 __attribute__((ext_vector_type(8)));
typedef float f32x4  __attribute__((ext_vector_type(4)));

namespace {

constexpr int CIN = 32, CO = 32, Himg = 128, Wimg = 128, SY = 32, Bb = 4;
constexpr int IMG = Himg * Wimg;                 // 16384
constexpr int NT  = Bb * CO * IMG;               // new_target elems
constexpr size_t WS_NEED = (size_t)(Bb * SY + Bb) * IMG * CIN * 2;  // 138,412,032 B

__device__ __forceinline__ unsigned cvtpk(float lo, float hi) {
  unsigned r;
  asm("v_cvt_pk_bf16_f32 %0, %1, %2" : "=v"(r) : "v"(lo), "v"(hi));
  return r;
}

// per-lane A fragments (weights) for one co-tile m; ci = cioff + kc*8 + j
__device__ __forceinline__ void load_w(bf16x8 wf[9],
                                       const float* __restrict__ Wfull,
                                       int cioff, int m, int lane)
{
  const int lx = lane & 15, kc = lane >> 4;
  #pragma unroll
  for (int tap = 0; tap < 9; ++tap) {
    const float* base = Wfull + (size_t)((m * 16 + lx) * 64 + cioff + kc * 8) * 9 + tap;
    bf16x8 w;
    #pragma unroll
    for (int j = 0; j < 8; ++j) {
      unsigned u = __builtin_bit_cast(unsigned, base[j * 9]);
      w[j] = (short)((u + 0x7FFFu + ((u >> 16) & 1u)) >> 16);
    }
    wf[tap] = w;
  }
}

// ======================= kernel T: NCHW f32 -> NHWC bf16 =======================
// block = 256 thr, handles 2 rows of one image (132 images x 64 chunks = 8448)
__global__ __launch_bounds__(256)
void transform_nhwc(const float* __restrict__ target,
                    const float* __restrict__ support,
                    unsigned short* __restrict__ ws)
{
  __shared__ unsigned lbuf[256 * 17];   // [px(256)][c2(16)] swizzled, pad-free

  const int tid   = threadIdx.x;
  const int img   = blockIdx.x >> 6;
  const int chunk = blockIdx.x & 63;
  const float* src = (img < Bb * SY)
      ? support + (size_t)img * CIN * IMG
      : target  + (size_t)(img - Bb * SY) * CIN * IMG;
  const int y0 = chunk * 2;

  // phase R: 1024 tasks = c2(16) x quad(64); coalesced f32x4 plane reads
  f32x4 a[4], bv[4];
  #pragma unroll
  for (int k = 0; k < 4; ++k) {
    const int task = tid + k * 256;
    const int c2 = task >> 6, quad = task & 63;
    const float* p = src + (size_t)(2 * c2) * IMG + y0 * Wimg + quad * 4;
    a[k]  = *reinterpret_cast<const f32x4*>(p);
    bv[k] = *reinterpret_cast<const f32x4*>(p + IMG);
  }
  #pragma unroll
  for (int k = 0; k < 4; ++k) {
    const int task = tid + k * 256;
    const int c2 = task >> 6, quad = task & 63;
    #pragma unroll
    for (int e = 0; e < 4; ++e) {
      const int px = quad * 4 + e;
      lbuf[px * 17 + (c2 ^ ((px >> 2) & 15))] = cvtpk(a[k][e], bv[k][e]);
    }
  }
  __syncthreads();

  // phase W: coalesced uint4 stores of [px][ci] bf16
  unsigned* dst32 = reinterpret_cast<unsigned*>(
      ws + (size_t)img * IMG * CIN + (size_t)y0 * Wimg * CIN);
  #pragma unroll
  for (int j = 0; j < 4; ++j) {
    const int t4 = (tid + j * 256) * 4;
    uint4 v;
    unsigned* vp = reinterpret_cast<unsigned*>(&v);
    #pragma unroll
    for (int e = 0; e < 4; ++e) {
      const int t = t4 + e;
      const int px = t >> 4, c2 = t & 15;
      vp[e] = lbuf[px * 17 + (c2 ^ ((px >> 2) & 15))];
    }
    *reinterpret_cast<uint4*>(dst32 + t4) = v;
  }
}

// ======================= kernel C: barrier-free NHWC conv =======================
__device__ __forceinline__ void conv_img(f32x4 acc[4],
                                         const unsigned short* __restrict__ img,
                                         const bf16x8 wf[9],
                                         int y, int x0, int lx, int kc)
{
  #pragma unroll
  for (int ky = 0; ky < 3; ++ky) {
    const int yy = y + ky - 1;
    if ((unsigned)yy >= (unsigned)Himg) continue;          // wave-uniform skip
    const unsigned short* rowp = img + (size_t)yy * (Wimg * CIN) + kc * 8;
    #pragma unroll
    for (int kx = 0; kx < 3; ++kx) {
      #pragma unroll
      for (int n = 0; n < 4; ++n) {
        const int xx = x0 + n * 16 + lx + kx - 1;
        bf16x8 bf = {0, 0, 0, 0, 0, 0, 0, 0};
        if ((unsigned)xx < (unsigned)Wimg)
          bf = *reinterpret_cast<const bf16x8*>(rowp + xx * CIN);
        acc[n] = __builtin_amdgcn_mfma_f32_16x16x32_bf16(wf[ky * 3 + kx], bf, acc[n], 0, 0, 0);
      }
    }
  }
}

__global__ __launch_bounds__(256, 3)
void conv_nhwc(const unsigned short* __restrict__ ws,
               const float* __restrict__ Wfull,
               const float* __restrict__ bias,
               float* __restrict__ out)
{
  // bijective XCD swizzle: each XCD owns contiguous eff-ranges (image-set locality)
  const int orig = blockIdx.x;
  const int eff  = (orig & 7) * 256 + (orig >> 3);
  const int yb  = eff & 63;
  const int xh  = (eff >> 6) & 1;
  const int syq = (eff >> 7) & 3;
  const int b   = eff >> 9;

  const int tid = threadIdx.x, lane = tid & 63, wv = tid >> 6;
  const int row = wv & 1, m = wv >> 1;
  const int lx = lane & 15, kc = lane >> 4;
  const int y  = yb * 2 + row;
  const int x0 = xh * 64;

  const unsigned short* tgt  = ws + (size_t)(Bb * SY + b) * IMG * CIN;
  const unsigned short* sup0 = ws + (size_t)(b * SY + syq * 8) * IMG * CIN;

  bf16x8 wf[9];
  load_w(wf, Wfull, 0, m, lane);                  // Wx

  f32x4 cx[4];
  #pragma unroll
  for (int n = 0; n < 4; ++n) cx[n] = f32x4{0.f, 0.f, 0.f, 0.f};
  conv_img(cx, tgt, wf, y, x0, lx, kc);
  #pragma unroll
  for (int j = 0; j < 4; ++j) {
    const float bvv = bias[m * 16 + kc * 4 + j];
    #pragma unroll
    for (int n = 0; n < 4; ++n) cx[n][j] += bvv;
  }

  load_w(wf, Wfull, 32, m, lane);                 // Wy

  f32x4 sum[4];
  #pragma unroll
  for (int n = 0; n < 4; ++n) sum[n] = f32x4{0.f, 0.f, 0.f, 0.f};

  for (int i = 0; i < 8; ++i) {
    const int sy = syq * 8 + i;
    const unsigned short* img = sup0 + (size_t)i * IMG * CIN;

    f32x4 acc[4];
    #pragma unroll
    for (int n = 0; n < 4; ++n) acc[n] = cx[n];
    conv_img(acc, img, wf, y, x0, lx, kc);

    #pragma unroll
    for (int n = 0; n < 4; ++n) {
      sum[n] += acc[n];
      const size_t basei = (size_t)NT +
          (((size_t)(b * SY + sy) * CO + m * 16 + kc * 4) * Himg + y) * Wimg +
          x0 + n * 16 + lx;
      #pragma unroll
      for (int j = 0; j < 4; ++j)
        out[basei + (size_t)j * IMG] = acc[n][j];
    }
  }

  // new_target partial (4 syq partials per element)
  #pragma unroll
  for (int n = 0; n < 4; ++n) {
    const size_t baseo =
        ((size_t)(b * CO + m * 16 + kc * 4) * Himg + y) * Wimg + x0 + n * 16 + lx;
    #pragma unroll
    for (int j = 0; j < 4; ++j) {
      const float cyPart = (sum[n][j] - 8.f * cx[n][j]) * (1.f / 32.f);
      const float v = cyPart + (syq == 0 ? cx[n][j] : 0.f);
      atomicAdd(&out[baseo + (size_t)j * IMG], v);
    }
  }
}

// ======================= fallback (round-4 kernel, used if ws too small) =======================
constexpr int TROWS = 6, TQ = 17, TCOLS = 70;
constexpr int NPIX  = TROWS * TCOLS;
constexpr int LDSB  = NPIX * 64;
constexpr int RTASK = TROWS * TQ;
constexpr int FB_NTHR = 512;
constexpr int FB_TPT  = 4;
constexpr int FB_SYC  = 8;

__device__ __forceinline__ int fb_swz(int pix, int cb) {
  return (pix * 64 + cb) ^ ((pix & 7) << 4);
}
__device__ __forceinline__ void fb_task_decode(int t, int& ch, int& row, int& q, bool& act) {
  ch = t & 15;
  const int r = t >> 4;
  row = r / TQ;
  q   = r - row * TQ;
  act = (r < RTASK);
}
__device__ __forceinline__ void fb_stage_load(f32x4 va[FB_TPT], f32x4 vb[FB_TPT],
                                              const float* __restrict__ src,
                                              int y0, int xq0, int tid)
{
  #pragma unroll
  for (int k = 0; k < FB_TPT; ++k) {
    int ch, row, q; bool act;
    fb_task_decode(tid + k * FB_NTHR, ch, row, q, act);
    const int y = y0 - 1 + row;
    act = act && ((unsigned)y < (unsigned)Himg);
    f32x4 v0 = {0.f, 0.f, 0.f, 0.f}, v1 = {0.f, 0.f, 0.f, 0.f};
    if (act) {
      const float* p = src + (size_t)(2 * ch) * IMG + y * Wimg + 4 * (xq0 + q);
      v0 = *reinterpret_cast<const f32x4*>(p);
      v1 = *reinterpret_cast<const f32x4*>(p + IMG);
    }
    va[k] = v0; vb[k] = v1;
  }
}
__device__ __forceinline__ void fb_stage_write(const f32x4 va[FB_TPT], const f32x4 vb[FB_TPT],
                                               char* __restrict__ lds,
                                               int y0, int xq0, int x0, int tid)
{
  #pragma unroll
  for (int k = 0; k < FB_TPT; ++k) {
    int ch, row, q; bool act;
    fb_task_decode(tid + k * FB_NTHR, ch, row, q, act);
    const int y = y0 - 1 + row;
    act = act && ((unsigned)y < (unsigned)Himg);
    if (act) {
      const int ix0 = 4 * (xq0 + q) - x0 + 1;
      #pragma unroll
      for (int e = 0; e < 4; ++e) {
        const int ix = ix0 + e;
        if (ix >= 0) {
          const int pix = row * TCOLS + ix;
          *reinterpret_cast<unsigned*>(lds + fb_swz(pix, ch * 4)) =
              cvtpk(va[k][e], vb[k][e]);
        }
      }
    }
  }
}
__device__ __forceinline__ void fb_conv1(f32x4 acc[4],
                                         const char* __restrict__ lds,
                                         const bf16x8 wf[9],
                                         int row, int lane)
{
  const int lx = lane & 15, kc = lane >> 4;
  #pragma unroll
  for (int ky = 0; ky < 3; ++ky) {
    #pragma unroll
    for (int kx = 0; kx < 3; ++kx) {
      const int tap = ky * 3 + kx;
      #pragma unroll
      for (int n = 0; n < 4; ++n) {
        const int p = (row + ky) * TCOLS + n * 16 + lx + kx;
        const bf16x8 bfrag = *reinterpret_cast<const bf16x8*>(lds + fb_swz(p, kc * 16));
        acc[n] = __builtin_amdgcn_mfma_f32_16x16x32_bf16(wf[tap], bfrag, acc[n], 0, 0, 0);
      }
    }
  }
}
__global__ __launch_bounds__(FB_NTHR, 4)
void fb_cross_mfma(const float* __restrict__ target,
                   const float* __restrict__ support,
                   const float* __restrict__ Wfull,
                   const float* __restrict__ bias,
                   float* __restrict__ out)
{
  __shared__ char lds[LDSB];
  const int tid  = threadIdx.x;
  const int lane = tid & 63;
  const int wv   = tid >> 6;
  const int row  = wv & 3;
  const int m    = wv >> 2;
  const int lx = lane & 15, kc = lane >> 4;
  const int bid = blockIdx.x;
  const int syq = bid & 3;
  const int xh  = (bid >> 2) & 1;
  const int yb  = (bid >> 3) & 31;
  const int b   = bid >> 8;
  const int y0 = yb * 4, x0 = xh * 64;
  const int y  = y0 + row;
  const int xq0 = xh ? 15 : 0;

  for (int e = tid; e < NPIX * 4; e += FB_NTHR)
    reinterpret_cast<f32x4*>(lds)[e] = f32x4{0.f, 0.f, 0.f, 0.f};

  bf16x8 wf[9];
  load_w(wf, Wfull, 0, m, lane);
  f32x4 va[FB_TPT], vb[FB_TPT];
  fb_stage_load(va, vb, target + (size_t)b * CIN * IMG, y0, xq0, tid);
  __syncthreads();
  fb_stage_write(va, vb, lds, y0, xq0, x0, tid);
  __syncthreads();

  f32x4 cx[4];
  #pragma unroll
  for (int n = 0; n < 4; ++n) cx[n] = f32x4{0.f, 0.f, 0.f, 0.f};
  fb_conv1(cx, lds, wf, row, lane);
  #pragma unroll
  for (int j = 0; j < 4; ++j) {
    const float bvv = bias[m * 16 + kc * 4 + j];
    #pragma unroll
    for (int n = 0; n < 4; ++n) cx[n][j] += bvv;
  }

  const float* supp0 = support + (size_t)(b * SY + syq * FB_SYC) * CIN * IMG;
  fb_stage_load(va, vb, supp0, y0, xq0, tid);
  load_w(wf, Wfull, 32, m, lane);
  __syncthreads();
  fb_stage_write(va, vb, lds, y0, xq0, x0, tid);

  f32x4 sum[4];
  #pragma unroll
  for (int n = 0; n < 4; ++n) sum[n] = f32x4{0.f, 0.f, 0.f, 0.f};
  __syncthreads();

  for (int i = 0; i < FB_SYC; ++i) {
    if (i < FB_SYC - 1)
      fb_stage_load(va, vb, supp0 + (size_t)(i + 1) * CIN * IMG, y0, xq0, tid);

    f32x4 acc[4];
    #pragma unroll
    for (int n = 0; n < 4; ++n) acc[n] = cx[n];
    fb_conv1(acc, lds, wf, row, lane);
    __syncthreads();

    if (i < FB_SYC - 1)
      fb_stage_write(va, vb, lds, y0, xq0, x0, tid);

    const int sy = syq * FB_SYC + i;
    #pragma unroll
    for (int n = 0; n < 4; ++n) {
      sum[n] += acc[n];
      const size_t basei = (size_t)NT +
          (((size_t)(b * SY + sy) * CO + m * 16 + kc * 4) * Himg + y) * Wimg +
          x0 + n * 16 + lx;
      #pragma unroll
      for (int j = 0; j < 4; ++j)
        out[basei + (size_t)j * IMG] = acc[n][j];
    }
    __syncthreads();
  }

  #pragma unroll
  for (int n = 0; n < 4; ++n) {
    const size_t baseo =
        ((size_t)(b * CO + m * 16 + kc * 4) * Himg + y) * Wimg + x0 + n * 16 + lx;
    #pragma unroll
    for (int j = 0; j < 4; ++j) {
      const float cyPart = (sum[n][j] - (float)FB_SYC * cx[n][j]) * (1.f / 32.f);
      const float v = cyPart + (syq == 0 ? cx[n][j] : 0.f);
      atomicAdd(&out[baseo + (size_t)j * IMG], v);
    }
  }
}

} // namespace

extern "C" void kernel_launch(void* const* d_in, const int* in_sizes, int n_in,
                              void* d_out, int out_size, void* d_ws, size_t ws_size,
                              hipStream_t stream)
{
  (void)in_sizes; (void)n_in; (void)out_size;
  const float* target  = (const float*)d_in[0];
  const float* support = (const float*)d_in[1];
  const float* Wfull   = (const float*)d_in[2];
  const float* bias    = (const float*)d_in[3];
  float* out = (float*)d_out;

  hipMemsetAsync(d_out, 0, (size_t)NT * sizeof(float), stream);

  if (ws_size >= WS_NEED) {
    unsigned short* ws = (unsigned short*)d_ws;
    transform_nhwc<<<dim3((Bb * SY + Bb) * 64), 256, 0, stream>>>(target, support, ws);
    conv_nhwc<<<dim3(2048), 256, 0, stream>>>(ws, Wfull, bias, out);
  } else {
    fb_cross_mfma<<<dim3(1024), FB_NTHR, 0, stream>>>(target, support, Wfull, bias, out);
  }
}

// Round 6
// 377.900 us; speedup vs baseline: 1.1255x; 1.0336x over previous
//
#include <hip/hip_runtime.h>

typedef short bf16x8 __attribute__((ext_vector_type(8)));
typedef float f32x4  __attribute__((ext_vector_type(4)));

namespace {

constexpr int CIN = 32, CO = 32, Himg = 128, Wimg = 128, SY = 32, Bb = 4;
constexpr int IMG = Himg * Wimg;                 // 16384
constexpr int NT  = Bb * CO * IMG;               // new_target elems
constexpr size_t WS_NEED = (size_t)(Bb * SY + Bb) * IMG * CIN * 2;  // 138,412,032 B

__device__ __forceinline__ unsigned cvtpk(float lo, float hi) {
  unsigned r;
  asm("v_cvt_pk_bf16_f32 %0, %1, %2" : "=v"(r) : "v"(lo), "v"(hi));
  return r;
}

// per-lane A fragments (weights) for one co-tile m; ci = cioff + kc*8 + j
__device__ __forceinline__ void load_w(bf16x8 wf[9],
                                       const float* __restrict__ Wfull,
                                       int cioff, int m, int lane)
{
  const int lx = lane & 15, kc = lane >> 4;
  #pragma unroll
  for (int tap = 0; tap < 9; ++tap) {
    const float* base = Wfull + (size_t)((m * 16 + lx) * 64 + cioff + kc * 8) * 9 + tap;
    bf16x8 w;
    #pragma unroll
    for (int j = 0; j < 8; ++j) {
      unsigned u = __builtin_bit_cast(unsigned, base[j * 9]);
      w[j] = (short)((u + 0x7FFFu + ((u >> 16) & 1u)) >> 16);
    }
    wf[tap] = w;
  }
}

// ======================= kernel T: NCHW f32 -> NHWC bf16 =======================
// block = 256 thr, handles 2 rows of one image (132 images x 64 chunks = 8448)
__global__ __launch_bounds__(256)
void transform_nhwc(const float* __restrict__ target,
                    const float* __restrict__ support,
                    unsigned short* __restrict__ ws)
{
  __shared__ unsigned lbuf[256 * 17];   // [px(256)][c2(16)] swizzled, pad-free

  const int tid   = threadIdx.x;
  const int img   = blockIdx.x >> 6;
  const int chunk = blockIdx.x & 63;
  const float* src = (img < Bb * SY)
      ? support + (size_t)img * CIN * IMG
      : target  + (size_t)(img - Bb * SY) * CIN * IMG;
  const int y0 = chunk * 2;

  // phase R: 1024 tasks = c2(16) x quad(64); coalesced f32x4 plane reads
  f32x4 a[4], bv[4];
  #pragma unroll
  for (int k = 0; k < 4; ++k) {
    const int task = tid + k * 256;
    const int c2 = task >> 6, quad = task & 63;
    const float* p = src + (size_t)(2 * c2) * IMG + y0 * Wimg + quad * 4;
    a[k]  = *reinterpret_cast<const f32x4*>(p);
    bv[k] = *reinterpret_cast<const f32x4*>(p + IMG);
  }
  #pragma unroll
  for (int k = 0; k < 4; ++k) {
    const int task = tid + k * 256;
    const int c2 = task >> 6, quad = task & 63;
    #pragma unroll
    for (int e = 0; e < 4; ++e) {
      const int px = quad * 4 + e;
      lbuf[px * 17 + (c2 ^ ((px >> 2) & 15))] = cvtpk(a[k][e], bv[k][e]);
    }
  }
  __syncthreads();

  // phase W: coalesced uint4 stores of [px][ci] bf16
  unsigned* dst32 = reinterpret_cast<unsigned*>(
      ws + (size_t)img * IMG * CIN + (size_t)y0 * Wimg * CIN);
  #pragma unroll
  for (int j = 0; j < 4; ++j) {
    const int t4 = (tid + j * 256) * 4;
    uint4 v;
    unsigned* vp = reinterpret_cast<unsigned*>(&v);
    #pragma unroll
    for (int e = 0; e < 4; ++e) {
      const int t = t4 + e;
      const int px = t >> 4, c2 = t & 15;
      vp[e] = lbuf[px * 17 + (c2 ^ ((px >> 2) & 15))];
    }
    *reinterpret_cast<uint4*>(dst32 + t4) = v;
  }
}

// ======================= kernel C: barrier-free NHWC conv =======================
__device__ __forceinline__ void conv_img(f32x4 acc[4],
                                         const unsigned short* __restrict__ img,
                                         const bf16x8 wf[9],
                                         int y, int x0, int lx, int kc)
{
  #pragma unroll
  for (int ky = 0; ky < 3; ++ky) {
    const int yy = y + ky - 1;
    if ((unsigned)yy >= (unsigned)Himg) continue;          // wave-uniform skip
    const unsigned short* rowp = img + (size_t)yy * (Wimg * CIN) + kc * 8;
    #pragma unroll
    for (int kx = 0; kx < 3; ++kx) {
      #pragma unroll
      for (int n = 0; n < 4; ++n) {
        const int xx = x0 + n * 16 + lx + kx - 1;
        bf16x8 bf = {0, 0, 0, 0, 0, 0, 0, 0};
        if ((unsigned)xx < (unsigned)Wimg)
          bf = *reinterpret_cast<const bf16x8*>(rowp + xx * CIN);
        acc[n] = __builtin_amdgcn_mfma_f32_16x16x32_bf16(wf[ky * 3 + kx], bf, acc[n], 0, 0, 0);
      }
    }
  }
}

__global__ __launch_bounds__(256, 3)
void conv_nhwc(const unsigned short* __restrict__ ws,
               const float* __restrict__ Wfull,
               const float* __restrict__ bias,
               float* __restrict__ out)
{
  // bijective XCD swizzle: each XCD owns contiguous eff-ranges (image-set locality)
  const int orig = blockIdx.x;
  const int eff  = (orig & 7) * 256 + (orig >> 3);
  const int yb  = eff & 63;
  const int xh  = (eff >> 6) & 1;
  const int syq = (eff >> 7) & 3;
  const int b   = eff >> 9;

  const int tid = threadIdx.x, lane = tid & 63, wv = tid >> 6;
  const int row = wv & 1, m = wv >> 1;
  const int lx = lane & 15, kc = lane >> 4;
  const int y  = yb * 2 + row;
  const int x0 = xh * 64;

  const unsigned short* tgt  = ws + (size_t)(Bb * SY + b) * IMG * CIN;
  const unsigned short* sup0 = ws + (size_t)(b * SY + syq * 8) * IMG * CIN;

  bf16x8 wf[9];
  load_w(wf, Wfull, 0, m, lane);                  // Wx

  f32x4 cx[4];
  #pragma unroll
  for (int n = 0; n < 4; ++n) cx[n] = f32x4{0.f, 0.f, 0.f, 0.f};
  conv_img(cx, tgt, wf, y, x0, lx, kc);
  #pragma unroll
  for (int j = 0; j < 4; ++j) {
    const float bvv = bias[m * 16 + kc * 4 + j];
    #pragma unroll
    for (int n = 0; n < 4; ++n) cx[n][j] += bvv;
  }

  load_w(wf, Wfull, 32, m, lane);                 // Wy

  f32x4 sum[4];
  #pragma unroll
  for (int n = 0; n < 4; ++n) sum[n] = f32x4{0.f, 0.f, 0.f, 0.f};

  for (int i = 0; i < 8; ++i) {
    const int sy = syq * 8 + i;
    const unsigned short* img = sup0 + (size_t)i * IMG * CIN;

    f32x4 acc[4];
    #pragma unroll
    for (int n = 0; n < 4; ++n) acc[n] = cx[n];
    conv_img(acc, img, wf, y, x0, lx, kc);

    #pragma unroll
    for (int n = 0; n < 4; ++n) {
      sum[n] += acc[n];
      const size_t basei = (size_t)NT +
          (((size_t)(b * SY + sy) * CO + m * 16 + kc * 4) * Himg + y) * Wimg +
          x0 + n * 16 + lx;
      #pragma unroll
      for (int j = 0; j < 4; ++j)
        out[basei + (size_t)j * IMG] = acc[n][j];
    }
  }

  // new_target partial (4 syq partials per element)
  #pragma unroll
  for (int n = 0; n < 4; ++n) {
    const size_t baseo =
        ((size_t)(b * CO + m * 16 + kc * 4) * Himg + y) * Wimg + x0 + n * 16 + lx;
    #pragma unroll
    for (int j = 0; j < 4; ++j) {
      const float cyPart = (sum[n][j] - 8.f * cx[n][j]) * (1.f / 32.f);
      const float v = cyPart + (syq == 0 ? cx[n][j] : 0.f);
      atomicAdd(&out[baseo + (size_t)j * IMG], v);
    }
  }
}

// ======================= fallback (round-4 kernel, used if ws too small) =======================
constexpr int TROWS = 6, TQ = 17, TCOLS = 70;
constexpr int NPIX  = TROWS * TCOLS;
constexpr int LDSB  = NPIX * 64;
constexpr int RTASK = TROWS * TQ;
constexpr int FB_NTHR = 512;
constexpr int FB_TPT  = 4;
constexpr int FB_SYC  = 8;

__device__ __forceinline__ int fb_swz(int pix, int cb) {
  return (pix * 64 + cb) ^ ((pix & 7) << 4);
}
__device__ __forceinline__ void fb_task_decode(int t, int& ch, int& row, int& q, bool& act) {
  ch = t & 15;
  const int r = t >> 4;
  row = r / TQ;
  q   = r - row * TQ;
  act = (r < RTASK);
}
__device__ __forceinline__ void fb_stage_load(f32x4 va[FB_TPT], f32x4 vb[FB_TPT],
                                              const float* __restrict__ src,
                                              int y0, int xq0, int tid)
{
  #pragma unroll
  for (int k = 0; k < FB_TPT; ++k) {
    int ch, row, q; bool act;
    fb_task_decode(tid + k * FB_NTHR, ch, row, q, act);
    const int y = y0 - 1 + row;
    act = act && ((unsigned)y < (unsigned)Himg);
    f32x4 v0 = {0.f, 0.f, 0.f, 0.f}, v1 = {0.f, 0.f, 0.f, 0.f};
    if (act) {
      const float* p = src + (size_t)(2 * ch) * IMG + y * Wimg + 4 * (xq0 + q);
      v0 = *reinterpret_cast<const f32x4*>(p);
      v1 = *reinterpret_cast<const f32x4*>(p + IMG);
    }
    va[k] = v0; vb[k] = v1;
  }
}
__device__ __forceinline__ void fb_stage_write(const f32x4 va[FB_TPT], const f32x4 vb[FB_TPT],
                                               char* __restrict__ lds,
                                               int y0, int xq0, int x0, int tid)
{
  #pragma unroll
  for (int k = 0; k < FB_TPT; ++k) {
    int ch, row, q; bool act;
    fb_task_decode(tid + k * FB_NTHR, ch, row, q, act);
    const int y = y0 - 1 + row;
    act = act && ((unsigned)y < (unsigned)Himg);
    if (act) {
      const int ix0 = 4 * (xq0 + q) - x0 + 1;
      #pragma unroll
      for (int e = 0; e < 4; ++e) {
        const int ix = ix0 + e;
        if (ix >= 0) {
          const int pix = row * TCOLS + ix;
          *reinterpret_cast<unsigned*>(lds + fb_swz(pix, ch * 4)) =
              cvtpk(va[k][e], vb[k][e]);
        }
      }
    }
  }
}
__device__ __forceinline__ void fb_conv1(f32x4 acc[4],
                                         const char* __restrict__ lds,
                                         const bf16x8 wf[9],
                                         int row, int lane)
{
  const int lx = lane & 15, kc = lane >> 4;
  #pragma unroll
  for (int ky = 0; ky < 3; ++ky) {
    #pragma unroll
    for (int kx = 0; kx < 3; ++kx) {
      const int tap = ky * 3 + kx;
      #pragma unroll
      for (int n = 0; n < 4; ++n) {
        const int p = (row + ky) * TCOLS + n * 16 + lx + kx;
        const bf16x8 bfrag = *reinterpret_cast<const bf16x8*>(lds + fb_swz(p, kc * 16));
        acc[n] = __builtin_amdgcn_mfma_f32_16x16x32_bf16(wf[tap], bfrag, acc[n], 0, 0, 0);
      }
    }
  }
}
__global__ __launch_bounds__(FB_NTHR, 4)
void fb_cross_mfma(const float* __restrict__ target,
                   const float* __restrict__ support,
                   const float* __restrict__ Wfull,
                   const float* __restrict__ bias,
                   float* __restrict__ out)
{
  __shared__ char lds[LDSB];
  const int tid  = threadIdx.x;
  const int lane = tid & 63;
  const int wv   = tid >> 6;
  const int row  = wv & 3;
  const int m    = wv >> 2;
  const int lx = lane & 15, kc = lane >> 4;
  const int bid = blockIdx.x;
  const int syq = bid & 3;
  const int xh  = (bid >> 2) & 1;
  const int yb  = (bid >> 3) & 31;
  const int b   = bid >> 8;
  const int y0 = yb * 4, x0 = xh * 64;
  const int y  = y0 + row;
  const int xq0 = xh ? 15 : 0;

  for (int e = tid; e < NPIX * 4; e += FB_NTHR)
    reinterpret_cast<f32x4*>(lds)[e] = f32x4{0.f, 0.f, 0.f, 0.f};

  bf16x8 wf[9];
  load_w(wf, Wfull, 0, m, lane);
  f32x4 va[FB_TPT], vb[FB_TPT];
  fb_stage_load(va, vb, target + (size_t)b * CIN * IMG, y0, xq0, tid);
  __syncthreads();
  fb_stage_write(va, vb, lds, y0, xq0, x0, tid);
  __syncthreads();

  f32x4 cx[4];
  #pragma unroll
  for (int n = 0; n < 4; ++n) cx[n] = f32x4{0.f, 0.f, 0.f, 0.f};
  fb_conv1(cx, lds, wf, row, lane);
  #pragma unroll
  for (int j = 0; j < 4; ++j) {
    const float bvv = bias[m * 16 + kc * 4 + j];
    #pragma unroll
    for (int n = 0; n < 4; ++n) cx[n][j] += bvv;
  }

  const float* supp0 = support + (size_t)(b * SY + syq * FB_SYC) * CIN * IMG;
  fb_stage_load(va, vb, supp0, y0, xq0, tid);
  load_w(wf, Wfull, 32, m, lane);
  __syncthreads();
  fb_stage_write(va, vb, lds, y0, xq0, x0, tid);

  f32x4 sum[4];
  #pragma unroll
  for (int n = 0; n < 4; ++n) sum[n] = f32x4{0.f, 0.f, 0.f, 0.f};
  __syncthreads();

  for (int i = 0; i < FB_SYC; ++i) {
    if (i < FB_SYC - 1)
      fb_stage_load(va, vb, supp0 + (size_t)(i + 1) * CIN * IMG, y0, xq0, tid);

    f32x4 acc[4];
    #pragma unroll
    for (int n = 0; n < 4; ++n) acc[n] = cx[n];
    fb_conv1(acc, lds, wf, row, lane);
    __syncthreads();

    if (i < FB_SYC - 1)
      fb_stage_write(va, vb, lds, y0, xq0, x0, tid);

    const int sy = syq * FB_SYC + i;
    #pragma unroll
    for (int n = 0; n < 4; ++n) {
      sum[n] += acc[n];
      const size_t basei = (size_t)NT +
          (((size_t)(b * SY + sy) * CO + m * 16 + kc * 4) * Himg + y) * Wimg +
          x0 + n * 16 + lx;
      #pragma unroll
      for (int j = 0; j < 4; ++j)
        out[basei + (size_t)j * IMG] = acc[n][j];
    }
    __syncthreads();
  }

  #pragma unroll
  for (int n = 0; n < 4; ++n) {
    const size_t baseo =
        ((size_t)(b * CO + m * 16 + kc * 4) * Himg + y) * Wimg + x0 + n * 16 + lx;
    #pragma unroll
    for (int j = 0; j < 4; ++j) {
      const float cyPart = (sum[n][j] - (float)FB_SYC * cx[n][j]) * (1.f / 32.f);
      const float v = cyPart + (syq == 0 ? cx[n][j] : 0.f);
      atomicAdd(&out[baseo + (size_t)j * IMG], v);
    }
  }
}

} // namespace

extern "C" void kernel_launch(void* const* d_in, const int* in_sizes, int n_in,
                              void* d_out, int out_size, void* d_ws, size_t ws_size,
                              hipStream_t stream)
{
  (void)in_sizes; (void)n_in; (void)out_size;
  const float* target  = (const float*)d_in[0];
  const float* support = (const float*)d_in[1];
  const float* Wfull   = (const float*)d_in[2];
  const float* bias    = (const float*)d_in[3];
  float* out = (float*)d_out;

  hipMemsetAsync(d_out, 0, (size_t)NT * sizeof(float), stream);

  if (ws_size >= WS_NEED) {
    unsigned short* ws = (unsigned short*)d_ws;
    transform_nhwc<<<dim3((Bb * SY + Bb) * 64), 256, 0, stream>>>(target, support, ws);
    conv_nhwc<<<dim3(2048), 256, 0, stream>>>(ws, Wfull, bias, out);
  } else {
    fb_cross_mfma<<<dim3(1024), FB_NTHR, 0, stream>>>(target, support, Wfull, bias, out);
  }
}

// Round 7
// 377.835 us; speedup vs baseline: 1.1257x; 1.0002x over previous
//
#include <hip/hip_runtime.h>

typedef short bf16x8 __attribute__((ext_vector_type(8)));
typedef float f32x4  __attribute__((ext_vector_type(4)));

namespace {

constexpr int CIN = 32, CO = 32, Himg = 128, Wimg = 128, SY = 32, Bb = 4;
constexpr int IMG = Himg * Wimg;                 // 16384
constexpr int NT  = Bb * CO * IMG;               // new_target elems
constexpr size_t WS_NEED = (size_t)(Bb * SY + Bb) * IMG * CIN * 2;  // 138,412,032 B

__device__ __forceinline__ unsigned cvtpk(float lo, float hi) {
  unsigned r;
  asm("v_cvt_pk_bf16_f32 %0, %1, %2" : "=v"(r) : "v"(lo), "v"(hi));
  return r;
}

// per-lane A fragments (weights) for one co-tile m; ci = cioff + kc*8 + j
__device__ __forceinline__ void load_w(bf16x8 wf[9],
                                       const float* __restrict__ Wfull,
                                       int cioff, int m, int lane)
{
  const int lx = lane & 15, kc = lane >> 4;
  #pragma unroll
  for (int tap = 0; tap < 9; ++tap) {
    const float* base = Wfull + (size_t)((m * 16 + lx) * 64 + cioff + kc * 8) * 9 + tap;
    bf16x8 w;
    #pragma unroll
    for (int j = 0; j < 8; ++j) {
      unsigned u = __builtin_bit_cast(unsigned, base[j * 9]);
      w[j] = (short)((u + 0x7FFFu + ((u >> 16) & 1u)) >> 16);
    }
    wf[tap] = w;
  }
}

// ======================= kernel T: NCHW f32 -> NHWC bf16 =======================
// block = 256 thr, handles 2 rows of one image (132 images x 64 chunks = 8448)
__global__ __launch_bounds__(256)
void transform_nhwc(const float* __restrict__ target,
                    const float* __restrict__ support,
                    unsigned short* __restrict__ ws)
{
  __shared__ unsigned lbuf[256 * 17];   // [px(256)][c2(16)] swizzled, pad-free

  const int tid   = threadIdx.x;
  const int img   = blockIdx.x >> 6;
  const int chunk = blockIdx.x & 63;
  const float* src = (img < Bb * SY)
      ? support + (size_t)img * CIN * IMG
      : target  + (size_t)(img - Bb * SY) * CIN * IMG;
  const int y0 = chunk * 2;

  // phase R: 1024 tasks = c2(16) x quad(64); coalesced f32x4 plane reads
  f32x4 a[4], bv[4];
  #pragma unroll
  for (int k = 0; k < 4; ++k) {
    const int task = tid + k * 256;
    const int c2 = task >> 6, quad = task & 63;
    const float* p = src + (size_t)(2 * c2) * IMG + y0 * Wimg + quad * 4;
    a[k]  = *reinterpret_cast<const f32x4*>(p);
    bv[k] = *reinterpret_cast<const f32x4*>(p + IMG);
  }
  #pragma unroll
  for (int k = 0; k < 4; ++k) {
    const int task = tid + k * 256;
    const int c2 = task >> 6, quad = task & 63;
    #pragma unroll
    for (int e = 0; e < 4; ++e) {
      const int px = quad * 4 + e;
      lbuf[px * 17 + (c2 ^ ((px >> 2) & 15))] = cvtpk(a[k][e], bv[k][e]);
    }
  }
  __syncthreads();

  // phase W: coalesced uint4 stores of [px][ci] bf16
  unsigned* dst32 = reinterpret_cast<unsigned*>(
      ws + (size_t)img * IMG * CIN + (size_t)y0 * Wimg * CIN);
  #pragma unroll
  for (int j = 0; j < 4; ++j) {
    const int t4 = (tid + j * 256) * 4;
    uint4 v;
    unsigned* vp = reinterpret_cast<unsigned*>(&v);
    #pragma unroll
    for (int e = 0; e < 4; ++e) {
      const int t = t4 + e;
      const int px = t >> 4, c2 = t & 15;
      vp[e] = lbuf[px * 17 + (c2 ^ ((px >> 2) & 15))];
    }
    *reinterpret_cast<uint4*>(dst32 + t4) = v;
  }
}

// ======================= kernel C: barrier-free NHWC conv =======================
__device__ __forceinline__ void conv_img(f32x4 acc[4],
                                         const unsigned short* __restrict__ img,
                                         const bf16x8 wf[9],
                                         int y, int x0, int lx, int kc)
{
  #pragma unroll
  for (int ky = 0; ky < 3; ++ky) {
    const int yy = y + ky - 1;
    if ((unsigned)yy >= (unsigned)Himg) continue;          // wave-uniform skip
    const unsigned short* rowp = img + (size_t)yy * (Wimg * CIN) + kc * 8;
    #pragma unroll
    for (int kx = 0; kx < 3; ++kx) {
      #pragma unroll
      for (int n = 0; n < 4; ++n) {
        const int xx = x0 + n * 16 + lx + kx - 1;
        bf16x8 bf = {0, 0, 0, 0, 0, 0, 0, 0};
        if ((unsigned)xx < (unsigned)Wimg)
          bf = *reinterpret_cast<const bf16x8*>(rowp + xx * CIN);
        acc[n] = __builtin_amdgcn_mfma_f32_16x16x32_bf16(wf[ky * 3 + kx], bf, acc[n], 0, 0, 0);
      }
    }
  }
}

__global__ __launch_bounds__(256, 3)
void conv_nhwc(const unsigned short* __restrict__ ws,
               const float* __restrict__ Wfull,
               const float* __restrict__ bias,
               float* __restrict__ out)
{
  // bijective XCD swizzle: each XCD owns contiguous eff-ranges (image-set locality)
  const int orig = blockIdx.x;
  const int eff  = (orig & 7) * 256 + (orig >> 3);
  const int yb  = eff & 63;
  const int xh  = (eff >> 6) & 1;
  const int syq = (eff >> 7) & 3;
  const int b   = eff >> 9;

  const int tid = threadIdx.x, lane = tid & 63, wv = tid >> 6;
  const int row = wv & 1, m = wv >> 1;
  const int lx = lane & 15, kc = lane >> 4;
  const int y  = yb * 2 + row;
  const int x0 = xh * 64;

  const unsigned short* tgt  = ws + (size_t)(Bb * SY + b) * IMG * CIN;
  const unsigned short* sup0 = ws + (size_t)(b * SY + syq * 8) * IMG * CIN;

  bf16x8 wf[9];
  load_w(wf, Wfull, 0, m, lane);                  // Wx

  f32x4 cx[4];
  #pragma unroll
  for (int n = 0; n < 4; ++n) cx[n] = f32x4{0.f, 0.f, 0.f, 0.f};
  conv_img(cx, tgt, wf, y, x0, lx, kc);
  #pragma unroll
  for (int j = 0; j < 4; ++j) {
    const float bvv = bias[m * 16 + kc * 4 + j];
    #pragma unroll
    for (int n = 0; n < 4; ++n) cx[n][j] += bvv;
  }

  load_w(wf, Wfull, 32, m, lane);                 // Wy

  f32x4 sum[4];
  #pragma unroll
  for (int n = 0; n < 4; ++n) sum[n] = f32x4{0.f, 0.f, 0.f, 0.f};

  for (int i = 0; i < 8; ++i) {
    const int sy = syq * 8 + i;
    const unsigned short* img = sup0 + (size_t)i * IMG * CIN;

    f32x4 acc[4];
    #pragma unroll
    for (int n = 0; n < 4; ++n) acc[n] = cx[n];
    conv_img(acc, img, wf, y, x0, lx, kc);

    #pragma unroll
    for (int n = 0; n < 4; ++n) {
      sum[n] += acc[n];
      const size_t basei = (size_t)NT +
          (((size_t)(b * SY + sy) * CO + m * 16 + kc * 4) * Himg + y) * Wimg +
          x0 + n * 16 + lx;
      #pragma unroll
      for (int j = 0; j < 4; ++j)
        out[basei + (size_t)j * IMG] = acc[n][j];
    }
  }

  // new_target partial (4 syq partials per element)
  #pragma unroll
  for (int n = 0; n < 4; ++n) {
    const size_t baseo =
        ((size_t)(b * CO + m * 16 + kc * 4) * Himg + y) * Wimg + x0 + n * 16 + lx;
    #pragma unroll
    for (int j = 0; j < 4; ++j) {
      const float cyPart = (sum[n][j] - 8.f * cx[n][j]) * (1.f / 32.f);
      const float v = cyPart + (syq == 0 ? cx[n][j] : 0.f);
      atomicAdd(&out[baseo + (size_t)j * IMG], v);
    }
  }
}

// ======================= fallback (round-4 kernel, used if ws too small) =======================
constexpr int TROWS = 6, TQ = 17, TCOLS = 70;
constexpr int NPIX  = TROWS * TCOLS;
constexpr int LDSB  = NPIX * 64;
constexpr int RTASK = TROWS * TQ;
constexpr int FB_NTHR = 512;
constexpr int FB_TPT  = 4;
constexpr int FB_SYC  = 8;

__device__ __forceinline__ int fb_swz(int pix, int cb) {
  return (pix * 64 + cb) ^ ((pix & 7) << 4);
}
__device__ __forceinline__ void fb_task_decode(int t, int& ch, int& row, int& q, bool& act) {
  ch = t & 15;
  const int r = t >> 4;
  row = r / TQ;
  q   = r - row * TQ;
  act = (r < RTASK);
}
__device__ __forceinline__ void fb_stage_load(f32x4 va[FB_TPT], f32x4 vb[FB_TPT],
                                              const float* __restrict__ src,
                                              int y0, int xq0, int tid)
{
  #pragma unroll
  for (int k = 0; k < FB_TPT; ++k) {
    int ch, row, q; bool act;
    fb_task_decode(tid + k * FB_NTHR, ch, row, q, act);
    const int y = y0 - 1 + row;
    act = act && ((unsigned)y < (unsigned)Himg);
    f32x4 v0 = {0.f, 0.f, 0.f, 0.f}, v1 = {0.f, 0.f, 0.f, 0.f};
    if (act) {
      const float* p = src + (size_t)(2 * ch) * IMG + y * Wimg + 4 * (xq0 + q);
      v0 = *reinterpret_cast<const f32x4*>(p);
      v1 = *reinterpret_cast<const f32x4*>(p + IMG);
    }
    va[k] = v0; vb[k] = v1;
  }
}
__device__ __forceinline__ void fb_stage_write(const f32x4 va[FB_TPT], const f32x4 vb[FB_TPT],
                                               char* __restrict__ lds,
                                               int y0, int xq0, int x0, int tid)
{
  #pragma unroll
  for (int k = 0; k < FB_TPT; ++k) {
    int ch, row, q; bool act;
    fb_task_decode(tid + k * FB_NTHR, ch, row, q, act);
    const int y = y0 - 1 + row;
    act = act && ((unsigned)y < (unsigned)Himg);
    if (act) {
      const int ix0 = 4 * (xq0 + q) - x0 + 1;
      #pragma unroll
      for (int e = 0; e < 4; ++e) {
        const int ix = ix0 + e;
        if (ix >= 0) {
          const int pix = row * TCOLS + ix;
          *reinterpret_cast<unsigned*>(lds + fb_swz(pix, ch * 4)) =
              cvtpk(va[k][e], vb[k][e]);
        }
      }
    }
  }
}
__device__ __forceinline__ void fb_conv1(f32x4 acc[4],
                                         const char* __restrict__ lds,
                                         const bf16x8 wf[9],
                                         int row, int lane)
{
  const int lx = lane & 15, kc = lane >> 4;
  #pragma unroll
  for (int ky = 0; ky < 3; ++ky) {
    #pragma unroll
    for (int kx = 0; kx < 3; ++kx) {
      const int tap = ky * 3 + kx;
      #pragma unroll
      for (int n = 0; n < 4; ++n) {
        const int p = (row + ky) * TCOLS + n * 16 + lx + kx;
        const bf16x8 bfrag = *reinterpret_cast<const bf16x8*>(lds + fb_swz(p, kc * 16));
        acc[n] = __builtin_amdgcn_mfma_f32_16x16x32_bf16(wf[tap], bfrag, acc[n], 0, 0, 0);
      }
    }
  }
}
__global__ __launch_bounds__(FB_NTHR, 4)
void fb_cross_mfma(const float* __restrict__ target,
                   const float* __restrict__ support,
                   const float* __restrict__ Wfull,
                   const float* __restrict__ bias,
                   float* __restrict__ out)
{
  __shared__ char lds[LDSB];
  const int tid  = threadIdx.x;
  const int lane = tid & 63;
  const int wv   = tid >> 6;
  const int row  = wv & 3;
  const int m    = wv >> 2;
  const int lx = lane & 15, kc = lane >> 4;
  const int bid = blockIdx.x;
  const int syq = bid & 3;
  const int xh  = (bid >> 2) & 1;
  const int yb  = (bid >> 3) & 31;
  const int b   = bid >> 8;
  const int y0 = yb * 4, x0 = xh * 64;
  const int y  = y0 + row;
  const int xq0 = xh ? 15 : 0;

  for (int e = tid; e < NPIX * 4; e += FB_NTHR)
    reinterpret_cast<f32x4*>(lds)[e] = f32x4{0.f, 0.f, 0.f, 0.f};

  bf16x8 wf[9];
  load_w(wf, Wfull, 0, m, lane);
  f32x4 va[FB_TPT], vb[FB_TPT];
  fb_stage_load(va, vb, target + (size_t)b * CIN * IMG, y0, xq0, tid);
  __syncthreads();
  fb_stage_write(va, vb, lds, y0, xq0, x0, tid);
  __syncthreads();

  f32x4 cx[4];
  #pragma unroll
  for (int n = 0; n < 4; ++n) cx[n] = f32x4{0.f, 0.f, 0.f, 0.f};
  fb_conv1(cx, lds, wf, row, lane);
  #pragma unroll
  for (int j = 0; j < 4; ++j) {
    const float bvv = bias[m * 16 + kc * 4 + j];
    #pragma unroll
    for (int n = 0; n < 4; ++n) cx[n][j] += bvv;
  }

  const float* supp0 = support + (size_t)(b * SY + syq * FB_SYC) * CIN * IMG;
  fb_stage_load(va, vb, supp0, y0, xq0, tid);
  load_w(wf, Wfull, 32, m, lane);
  __syncthreads();
  fb_stage_write(va, vb, lds, y0, xq0, x0, tid);

  f32x4 sum[4];
  #pragma unroll
  for (int n = 0; n < 4; ++n) sum[n] = f32x4{0.f, 0.f, 0.f, 0.f};
  __syncthreads();

  for (int i = 0; i < FB_SYC; ++i) {
    if (i < FB_SYC - 1)
      fb_stage_load(va, vb, supp0 + (size_t)(i + 1) * CIN * IMG, y0, xq0, tid);

    f32x4 acc[4];
    #pragma unroll
    for (int n = 0; n < 4; ++n) acc[n] = cx[n];
    fb_conv1(acc, lds, wf, row, lane);
    __syncthreads();

    if (i < FB_SYC - 1)
      fb_stage_write(va, vb, lds, y0, xq0, x0, tid);

    const int sy = syq * FB_SYC + i;
    #pragma unroll
    for (int n = 0; n < 4; ++n) {
      sum[n] += acc[n];
      const size_t basei = (size_t)NT +
          (((size_t)(b * SY + sy) * CO + m * 16 + kc * 4) * Himg + y) * Wimg +
          x0 + n * 16 + lx;
      #pragma unroll
      for (int j = 0; j < 4; ++j)
        out[basei + (size_t)j * IMG] = acc[n][j];
    }
    __syncthreads();
  }

  #pragma unroll
  for (int n = 0; n < 4; ++n) {
    const size_t baseo =
        ((size_t)(b * CO + m * 16 + kc * 4) * Himg + y) * Wimg + x0 + n * 16 + lx;
    #pragma unroll
    for (int j = 0; j < 4; ++j) {
      const float cyPart = (sum[n][j] - (float)FB_SYC * cx[n][j]) * (1.f / 32.f);
      const float v = cyPart + (syq == 0 ? cx[n][j] : 0.f);
      atomicAdd(&out[baseo + (size_t)j * IMG], v);
    }
  }
}

} // namespace

extern "C" void kernel_launch(void* const* d_in, const int* in_sizes, int n_in,
                              void* d_out, int out_size, void* d_ws, size_t ws_size,
                              hipStream_t stream)
{
  (void)in_sizes; (void)n_in; (void)out_size;
  const float* target  = (const float*)d_in[0];
  const float* support = (const float*)d_in[1];
  const float* Wfull   = (const float*)d_in[2];
  const float* bias    = (const float*)d_in[3];
  float* out = (float*)d_out;

  hipMemsetAsync(d_out, 0, (size_t)NT * sizeof(float), stream);

  if (ws_size >= WS_NEED) {
    unsigned short* ws = (unsigned short*)d_ws;
    transform_nhwc<<<dim3((Bb * SY + Bb) * 64), 256, 0, stream>>>(target, support, ws);
    conv_nhwc<<<dim3(2048), 256, 0, stream>>>(ws, Wfull, bias, out);
  } else {
    fb_cross_mfma<<<dim3(1024), FB_NTHR, 0, stream>>>(target, support, Wfull, bias, out);
  }
}